// Round 5
// baseline (1543.535 us; speedup 1.0000x reference)
//
#include <hip/hip_runtime.h>
#include <math.h>

typedef __attribute__((ext_vector_type(4))) float f32x4;
typedef __attribute__((ext_vector_type(8))) short bf16x8;

namespace {
constexpr int B_ = 4, C_ = 512, N_ = 4096;
constexpr int JT  = 64;            // query columns per WG
constexpr int IB  = 256;           // key rows per flash iteration
constexpr int KC  = 32;            // channel chunk per MFMA sweep
constexpr int NCH = C_ / KC;       // 16
constexpr int NIB = N_ / IB;       // 16
}

__device__ __forceinline__ unsigned short f2bf(float f) {
    unsigned int u = __float_as_uint(f);
    u = (u + 0x7fffu + ((u >> 16) & 1u)) >> 16;
    return (unsigned short)u;
}
__device__ __forceinline__ float bf2f(unsigned short h) {
    return __uint_as_float(((unsigned int)h) << 16);
}

// ---------- pre-pass 1: X[b][c][i] f32 -> fragment-tiled bf16 hi/lo ----------
// layout: [b][tile16 (i or j)][ck (c/32)][lg (c8-group)][lr (row-in-tile)][e (c elem)]
// offset = (b<<21) + (tile<<13) + (ck<<9) + (lg<<7) + (lr<<3) + e
__global__ __launch_bounds__(256)
void cvt_tiled_split(const float* __restrict__ X,
                     unsigned short* __restrict__ Xh,
                     unsigned short* __restrict__ Xl)
{
    __shared__ float tile[64][66];
    const int t    = (int)threadIdx.x;
    const int blk  = (int)blockIdx.x;
    const int b    = blk >> 9;
    const int r    = blk & 511;
    const int it64 = r >> 3;             // 64-row supertile (i/j dim)
    const int ct64 = r & 7;              // 64-channel supertile

    const float* src = X + ((size_t)(b * C_ + ct64 * 64)) * N_ + it64 * 64;
    #pragma unroll
    for (int rep = 0; rep < 4; ++rep) {
        int idx = rep * 256 + t;
        int c   = idx >> 4;
        int i4  = (idx & 15) * 4;
        const float4 v = *(const float4*)(src + (size_t)c * N_ + i4);
        tile[c][i4 + 0] = v.x; tile[c][i4 + 1] = v.y;
        tile[c][i4 + 2] = v.z; tile[c][i4 + 3] = v.w;
    }
    __syncthreads();
    #pragma unroll
    for (int half = 0; half < 2; ++half) {
        const int f  = half * 256 + t;       // 0..511 write-groups of 16 B
        const int lr = f & 15;
        const int lg = (f >> 4) & 3;
        const int l  = (f >> 6) & 1;
        const int gi = f >> 7;
        const int itile = it64 * 4 + gi;
        const int ck    = ct64 * 2 + l;
        const int off   = (b << 21) + (itile << 13) + (ck << 9) + (lg << 7) + (lr << 3);
        unsigned short hv[8], lv[8];
        #pragma unroll
        for (int e = 0; e < 8; ++e) {
            float v = tile[l * 32 + lg * 8 + e][gi * 16 + lr];
            unsigned short h = f2bf(v);
            hv[e] = h;
            lv[e] = f2bf(v - bf2f(h));
        }
        *(uint4*)(Xh + off) = *(const uint4*)hv;
        *(uint4*)(Xl + off) = *(const uint4*)lv;
    }
}

// ---------- pre-pass 2: V[b][c][i] f32 -> fragment-tiled bf16 (hi only) ----------
// layout: [b][ctile (c/16)][ik (i/32)][lg (i8-group)][lr (c-in-tile)][e (i elem)]
// offset = (b<<21) + (ctile<<16) + (ik<<9) + (lg<<7) + (lr<<3) + e
__global__ __launch_bounds__(256)
void cvt_v_tiled(const float* __restrict__ X, unsigned short* __restrict__ Xp)
{
    const int gid   = (int)blockIdx.x * 256 + (int)threadIdx.x;
    const int lr    = gid & 15;
    const int lg    = (gid >> 4) & 3;
    const int ik    = (gid >> 6) & 127;
    const int ctile = (gid >> 13) & 31;
    const int b     = gid >> 18;
    const int c     = ctile * 16 + lr;
    const int i     = ik * 32 + lg * 8;
    const float* s  = X + ((size_t)(b * C_ + c)) * N_ + i;
    const float4 a  = *(const float4*)s;
    const float4 d  = *(const float4*)(s + 4);
    unsigned short hv[8];
    hv[0] = f2bf(a.x); hv[1] = f2bf(a.y); hv[2] = f2bf(a.z); hv[3] = f2bf(a.w);
    hv[4] = f2bf(d.x); hv[5] = f2bf(d.y); hv[6] = f2bf(d.z); hv[7] = f2bf(d.w);
    const int off = (b << 21) + (ctile << 16) + (ik << 9) + (lg << 7) + (lr << 3);
    *(uint4*)(Xp + off) = *(const uint4*)hv;
}

// ---------- main fused flash-attention: direct-fragment MFMA, barrier-light ----------
// grid 256 (1 WG/CU), 1024 threads = 16 waves. Phase A: iw=w>>1 (32 i-rows),
// jw=w&1 (32 j-cols); zero LDS, zero barriers. Phase B: wave w owns 32 channels.
__global__ __launch_bounds__(1024)
void attn_mfma4(const unsigned short* __restrict__ Kph,
                const unsigned short* __restrict__ Kpl,
                const unsigned short* __restrict__ Qph,
                const unsigned short* __restrict__ Qpl,
                const unsigned short* __restrict__ Vp,
                const float* __restrict__ Qorig,
                float* __restrict__ Out)
{
    __shared__ unsigned short Pt[JT * IB];    // 32 KB, XOR-swizzled [j][i] bf16
    __shared__ float red_max[8][JT];
    __shared__ float red_sum[8][JT];

    const int t    = (int)threadIdx.x;
    const int w    = t >> 6;
    const int lane = t & 63;
    const int lr   = lane & 15;
    const int lg   = lane >> 4;
    const int iw   = w >> 1;      // 0..7 : i-strip of 32 (phase A)
    const int jw   = w & 1;       // 0..1 : j-half of 32  (phase A)

    // XCD swizzle: 32 consecutive j-tiles (same batch) per XCD -> Q fits L2
    const int bidl = ((int)blockIdx.x & 7) * 32 + ((int)blockIdx.x >> 3);
    const int b    = bidl >> 6;
    const int j0   = (bidl & 63) * JT;

    const int fb  = (lg << 7) + (lr << 3);   // within-fragment offset
    const int bb  = b << 21;
    const int jt0 = (j0 >> 4) + jw * 2;      // Q tile16 base for this wave

    float m_run = -INFINITY;     // lane = j (redundant per wave)
    float l_run = 0.0f;

    f32x4 Oacc[2][4];
    #pragma unroll
    for (int a = 0; a < 2; ++a)
        #pragma unroll
        for (int c = 0; c < 4; ++c) Oacc[a][c] = (f32x4)0.0f;

    for (int ib = 0; ib < NIB; ++ib) {
        const int i0  = ib * IB;
        const int it0 = (i0 >> 4) + iw * 2;  // K tile16 base for this wave

        f32x4 Sacc[2][2];
        #pragma unroll
        for (int x = 0; x < 2; ++x)
            #pragma unroll
            for (int y = 0; y < 2; ++y) Sacc[x][y] = (f32x4)0.0f;

        // ---- phase A: S += K^T Q, direct fragment loads, NO barriers ----
        #pragma unroll
        for (int ck = 0; ck < NCH; ++ck) {
            const int co = (ck << 9) + fb;
            const bf16x8 akh0 = *(const bf16x8*)(Kph + bb + ((it0 + 0) << 13) + co);
            const bf16x8 akh1 = *(const bf16x8*)(Kph + bb + ((it0 + 1) << 13) + co);
            const bf16x8 akl0 = *(const bf16x8*)(Kpl + bb + ((it0 + 0) << 13) + co);
            const bf16x8 akl1 = *(const bf16x8*)(Kpl + bb + ((it0 + 1) << 13) + co);
            const bf16x8 bqh0 = *(const bf16x8*)(Qph + bb + ((jt0 + 0) << 13) + co);
            const bf16x8 bqh1 = *(const bf16x8*)(Qph + bb + ((jt0 + 1) << 13) + co);
            const bf16x8 bql0 = *(const bf16x8*)(Qpl + bb + ((jt0 + 0) << 13) + co);
            const bf16x8 bql1 = *(const bf16x8*)(Qpl + bb + ((jt0 + 1) << 13) + co);

            Sacc[0][0] = __builtin_amdgcn_mfma_f32_16x16x32_bf16(akh0, bqh0, Sacc[0][0], 0, 0, 0);
            Sacc[0][0] = __builtin_amdgcn_mfma_f32_16x16x32_bf16(akh0, bql0, Sacc[0][0], 0, 0, 0);
            Sacc[0][0] = __builtin_amdgcn_mfma_f32_16x16x32_bf16(akl0, bqh0, Sacc[0][0], 0, 0, 0);
            Sacc[0][1] = __builtin_amdgcn_mfma_f32_16x16x32_bf16(akh0, bqh1, Sacc[0][1], 0, 0, 0);
            Sacc[0][1] = __builtin_amdgcn_mfma_f32_16x16x32_bf16(akh0, bql1, Sacc[0][1], 0, 0, 0);
            Sacc[0][1] = __builtin_amdgcn_mfma_f32_16x16x32_bf16(akl0, bqh1, Sacc[0][1], 0, 0, 0);
            Sacc[1][0] = __builtin_amdgcn_mfma_f32_16x16x32_bf16(akh1, bqh0, Sacc[1][0], 0, 0, 0);
            Sacc[1][0] = __builtin_amdgcn_mfma_f32_16x16x32_bf16(akh1, bql0, Sacc[1][0], 0, 0, 0);
            Sacc[1][0] = __builtin_amdgcn_mfma_f32_16x16x32_bf16(akl1, bqh0, Sacc[1][0], 0, 0, 0);
            Sacc[1][1] = __builtin_amdgcn_mfma_f32_16x16x32_bf16(akh1, bqh1, Sacc[1][1], 0, 0, 0);
            Sacc[1][1] = __builtin_amdgcn_mfma_f32_16x16x32_bf16(akh1, bql1, Sacc[1][1], 0, 0, 0);
            Sacc[1][1] = __builtin_amdgcn_mfma_f32_16x16x32_bf16(akl1, bqh1, Sacc[1][1], 0, 0, 0);
        }

        // ---- per-column block max -> red_max[iw][j] ----
        #pragma unroll
        for (int jt = 0; jt < 2; ++jt) {
            float mx = -INFINITY;
            #pragma unroll
            for (int it = 0; it < 2; ++it)
                #pragma unroll
                for (int r = 0; r < 4; ++r) mx = fmaxf(mx, Sacc[it][jt][r]);
            mx = fmaxf(mx, __shfl_xor(mx, 16));
            mx = fmaxf(mx, __shfl_xor(mx, 32));
            if (lane < 16) red_max[iw][jw * 32 + jt * 16 + lane] = mx;
        }
        __syncthreads();   // bar1

        // ---- running max + scale (redundant per wave, lane = j) ----
        float bm = red_max[0][lane];
        #pragma unroll
        for (int g = 1; g < 8; ++g) bm = fmaxf(bm, red_max[g][lane]);
        const float m_new = fmaxf(m_run, bm);
        const float scale = __expf(m_run - m_new);
        m_run = m_new;

        // ---- exp, Pt write (swizzled), partial sums ----
        #pragma unroll
        for (int jt = 0; jt < 2; ++jt) {
            const int j = jw * 32 + jt * 16 + lr;
            const float mcol = __shfl(m_new, j);
            float csum = 0.0f;
            #pragma unroll
            for (int it = 0; it < 2; ++it) {
                const float p0 = __expf(Sacc[it][jt][0] - mcol);
                const float p1 = __expf(Sacc[it][jt][1] - mcol);
                const float p2 = __expf(Sacc[it][jt][2] - mcol);
                const float p3 = __expf(Sacc[it][jt][3] - mcol);
                csum += (p0 + p1) + (p2 + p3);
                ushort4 pk;
                pk.x = f2bf(p0); pk.y = f2bf(p1); pk.z = f2bf(p2); pk.w = f2bf(p3);
                const unsigned byteoff =
                    ((unsigned)(j * (IB * 2) + iw * 64 + it * 32 + lg * 8)) ^
                    (((unsigned)(lr & 7)) << 4);
                *(ushort4*)((char*)Pt + byteoff) = pk;
            }
            csum += __shfl_xor(csum, 16);
            csum += __shfl_xor(csum, 32);
            if (lane < 16) red_sum[iw][j] = csum;
        }
        // ---- O rescale (phase-B mapping: j = jt*16+lr) ----
        {
            float scB[4];
            #pragma unroll
            for (int jt = 0; jt < 4; ++jt) scB[jt] = __shfl(scale, jt * 16 + lr);
            #pragma unroll
            for (int ct = 0; ct < 2; ++ct)
                #pragma unroll
                for (int jt = 0; jt < 4; ++jt) {
                    Oacc[ct][jt][0] *= scB[jt];
                    Oacc[ct][jt][1] *= scB[jt];
                    Oacc[ct][jt][2] *= scB[jt];
                    Oacc[ct][jt][3] *= scB[jt];
                }
        }
        __syncthreads();   // bar2

        // ---- running denominator ----
        l_run = l_run * scale +
                ((red_sum[0][lane] + red_sum[1][lane]) + (red_sum[2][lane] + red_sum[3][lane])) +
                ((red_sum[4][lane] + red_sum[5][lane]) + (red_sum[6][lane] + red_sum[7][lane]));

        // ---- phase B: Oacc += V_block * P (V direct from tiled global) ----
        const int ikb = (i0 >> 5);
        #pragma unroll
        for (int ks = 0; ks < 8; ++ks) {
            bf16x8 pf[4];
            #pragma unroll
            for (int jt = 0; jt < 4; ++jt) {
                const int j = jt * 16 + lr;
                const unsigned byteoff =
                    ((unsigned)(j * (IB * 2) + ks * 64 + lg * 16)) ^
                    (((unsigned)(lr & 7)) << 4);
                pf[jt] = *(const bf16x8*)((char*)Pt + byteoff);
            }
            #pragma unroll
            for (int ct = 0; ct < 2; ++ct) {
                const int vidx = bb + ((w * 2 + ct) << 16) + ((ikb + ks) << 9) + fb;
                const bf16x8 vf = *(const bf16x8*)(Vp + vidx);
                #pragma unroll
                for (int jt = 0; jt < 4; ++jt)
                    Oacc[ct][jt] = __builtin_amdgcn_mfma_f32_16x16x32_bf16(vf, pf[jt], Oacc[ct][jt], 0, 0, 0);
            }
        }
    }

    // ---- epilogue: out = q + Oacc / l ----
    {
        float il[4];
        #pragma unroll
        for (int jt = 0; jt < 4; ++jt) il[jt] = 1.0f / __shfl(l_run, jt * 16 + lr);
        #pragma unroll
        for (int ct = 0; ct < 2; ++ct) {
            #pragma unroll
            for (int r = 0; r < 4; ++r) {
                const int c = w * 32 + ct * 16 + lg * 4 + r;
                const float* qrow = Qorig + ((size_t)(b * C_ + c)) * N_ + j0;
                float*       orow = Out   + ((size_t)(b * C_ + c)) * N_ + j0;
                #pragma unroll
                for (int jt = 0; jt < 4; ++jt) {
                    const int j = jt * 16 + lr;
                    orow[j] = qrow[j] + Oacc[ct][jt][r] * il[jt];
                }
            }
        }
    }
}

// ---------- fallback (round-1 f32 kernel) if workspace is too small ----------
namespace {
constexpr int FJT = 32, FIB = 64, FTPB = 256, FNJT = N_ / FJT;
}
__global__ __launch_bounds__(FTPB, 2)
void attn_fused_f32(const float* __restrict__ Q,
                    const float* __restrict__ K,
                    const float* __restrict__ V,
                    float* __restrict__ O)
{
    __shared__ float q_lds[C_][FJT];
    __shared__ float p_t[FJT][FIB + 4];
    __shared__ float red_max[8][FJT];
    __shared__ float red_sum[8][FJT];

    const int t  = (int)threadIdx.x;
    const int j  = t & (FJT - 1);
    const int g  = t >> 5;
    const int b  = (int)blockIdx.x / FNJT;
    const int j0 = ((int)blockIdx.x % FNJT) * FJT;

    const float* Qb = Q + ((size_t)b * C_) * N_ + j0;
    const float* Kb = K + ((size_t)b * C_) * N_;
    const float* Vb = V + ((size_t)b * C_) * N_;
    float*       Ob = O + ((size_t)b * C_) * N_ + j0;

    #pragma unroll 4
    for (int r = 0; r < (C_ * FJT) / FTPB; ++r) {
        int idx = r * FTPB + t;
        q_lds[idx >> 5][idx & (FJT - 1)] = Qb[(size_t)(idx >> 5) * N_ + (idx & (FJT - 1))];
    }
    __syncthreads();

    float acc[64];
    #pragma unroll
    for (int x = 0; x < 64; ++x) acc[x] = 0.0f;
    float m_run = -INFINITY, l_run = 0.0f;

    for (int i0 = 0; i0 < N_; i0 += FIB) {
        float s_acc[8];
        #pragma unroll
        for (int r = 0; r < 8; ++r) s_acc[r] = 0.0f;
        const float* kp = Kb + i0 + g * 8;
        #pragma unroll 4
        for (int c = 0; c < C_; ++c) {
            float qv = q_lds[c][j];
            const float4 k0 = *(const float4*)(kp + (size_t)c * N_);
            const float4 k1 = *(const float4*)(kp + (size_t)c * N_ + 4);
            s_acc[0] = fmaf(k0.x, qv, s_acc[0]); s_acc[1] = fmaf(k0.y, qv, s_acc[1]);
            s_acc[2] = fmaf(k0.z, qv, s_acc[2]); s_acc[3] = fmaf(k0.w, qv, s_acc[3]);
            s_acc[4] = fmaf(k1.x, qv, s_acc[4]); s_acc[5] = fmaf(k1.y, qv, s_acc[5]);
            s_acc[6] = fmaf(k1.z, qv, s_acc[6]); s_acc[7] = fmaf(k1.w, qv, s_acc[7]);
        }
        float tmax = fmaxf(fmaxf(fmaxf(s_acc[0], s_acc[1]), fmaxf(s_acc[2], s_acc[3])),
                           fmaxf(fmaxf(s_acc[4], s_acc[5]), fmaxf(s_acc[6], s_acc[7])));
        red_max[g][j] = tmax;
        __syncthreads();
        float bmax = red_max[0][j];
        #pragma unroll
        for (int gg = 1; gg < 8; ++gg) bmax = fmaxf(bmax, red_max[gg][j]);
        float new_m = fmaxf(m_run, bmax);
        float scale = __expf(m_run - new_m);
        float psum = 0.0f, pv[8];
        #pragma unroll
        for (int r = 0; r < 8; ++r) { pv[r] = __expf(s_acc[r] - new_m); psum += pv[r]; }
        #pragma unroll
        for (int r = 0; r < 8; ++r) p_t[j][g * 8 + r] = pv[r];
        red_sum[g][j] = psum;
        __syncthreads();
        float bsum = 0.0f;
        #pragma unroll
        for (int gg = 0; gg < 8; ++gg) bsum += red_sum[gg][j];
        l_run = l_run * scale + bsum;
        m_run = new_m;
        #pragma unroll
        for (int x = 0; x < 64; ++x) acc[x] *= scale;
        const float* vp = Vb + (size_t)(g * 64) * N_ + i0;
        for (int i4 = 0; i4 < 16; ++i4) {
            const float4 p4 = *(const float4*)&p_t[j][i4 * 4];
            const float* vpi = vp + i4 * 4;
            #pragma unroll
            for (int cq = 0; cq < 4; ++cq) {
                #pragma unroll
                for (int ci = 0; ci < 16; ++ci) {
                    const int cc = cq * 16 + ci;
                    const float4 vv = *(const float4*)(vpi + (size_t)cc * N_);
                    acc[cc] = fmaf(vv.x, p4.x, acc[cc]);
                    acc[cc] = fmaf(vv.y, p4.y, acc[cc]);
                    acc[cc] = fmaf(vv.z, p4.z, acc[cc]);
                    acc[cc] = fmaf(vv.w, p4.w, acc[cc]);
                }
                asm volatile("" ::: "memory");
            }
        }
    }
    const float inv_l = 1.0f / l_run;
    #pragma unroll
    for (int cc = 0; cc < 64; ++cc) {
        const int c = g * 64 + cc;
        Ob[(size_t)c * N_ + j] = q_lds[c][j] + acc[cc] * inv_l;
    }
}

extern "C" void kernel_launch(void* const* d_in, const int* in_sizes, int n_in,
                              void* d_out, int out_size, void* d_ws, size_t ws_size,
                              hipStream_t stream) {
    const float* Q = (const float*)d_in[0];
    const float* K = (const float*)d_in[1];
    const float* V = (const float*)d_in[2];
    float* O = (float*)d_out;

    const size_t EL   = (size_t)B_ * C_ * N_;   // 8388608 elements
    const size_t NEED = EL * 2 * 5;             // 5 bf16 arrays = 80 MiB

    if (ws_size >= NEED) {
        unsigned short* Kph = (unsigned short*)d_ws;
        unsigned short* Kpl = Kph + EL;
        unsigned short* Qph = Kpl + EL;
        unsigned short* Qpl = Qph + EL;
        unsigned short* Vpp = Qpl + EL;
        cvt_tiled_split<<<dim3(2048), dim3(256), 0, stream>>>(K, Kph, Kpl);
        cvt_tiled_split<<<dim3(2048), dim3(256), 0, stream>>>(Q, Qph, Qpl);
        cvt_v_tiled<<<dim3(4096), dim3(256), 0, stream>>>(V, Vpp);
        attn_mfma4<<<dim3(256), dim3(1024), 0, stream>>>(Kph, Kpl, Qph, Qpl, Vpp, Q, O);
    } else {
        attn_fused_f32<<<dim3(B_ * FNJT), dim3(FTPB), 0, stream>>>(Q, K, V, O);
    }
}

// Round 6
// 612.562 us; speedup vs baseline: 2.5198x; 2.5198x over previous
//
#include <hip/hip_runtime.h>
#include <math.h>

typedef __attribute__((ext_vector_type(4))) float f32x4;
typedef __attribute__((ext_vector_type(8))) short bf16x8;

namespace {
constexpr int B_ = 4, C_ = 512, N_ = 4096;
constexpr int JT  = 64;            // query columns per WG
constexpr int IB  = 128;           // key rows per flash iteration
constexpr int KC  = 32;            // channel chunk staged in LDS
constexpr int NCH = C_ / KC;       // 16
constexpr int NIB = N_ / IB;       // 32
}

__device__ __forceinline__ unsigned short f2bf(float f) {
    unsigned int u = __float_as_uint(f);
    u = (u + 0x7fffu + ((u >> 16) & 1u)) >> 16;
    return (unsigned short)u;
}
__device__ __forceinline__ float bf2f(unsigned short h) {
    return __uint_as_float(((unsigned int)h) << 16);
}

// ---------- pre-pass 1: X[b][c][i] (f32) -> Xt hi/lo [b][i][c] (bf16 split) ----------
__global__ __launch_bounds__(256)
void cvt_transpose_split(const float* __restrict__ X,
                         unsigned short* __restrict__ Xh,
                         unsigned short* __restrict__ Xl)
{
    __shared__ float tile[64][66];
    const int t   = (int)threadIdx.x;
    const int blk = (int)blockIdx.x;
    const int b   = blk >> 9;
    const int r   = blk & 511;
    const int it  = r >> 3;
    const int ct  = r & 7;

    const float* src = X + ((size_t)(b * C_ + ct * 64)) * N_ + it * 64;
    #pragma unroll
    for (int rep = 0; rep < 4; ++rep) {
        int idx = rep * 256 + t;
        int c   = idx >> 4;
        int i4  = (idx & 15) * 4;
        const float4 v = *(const float4*)(src + (size_t)c * N_ + i4);
        tile[c][i4 + 0] = v.x; tile[c][i4 + 1] = v.y;
        tile[c][i4 + 2] = v.z; tile[c][i4 + 3] = v.w;
    }
    __syncthreads();
    unsigned short* dh = Xh + ((size_t)(b * N_ + it * 64)) * C_ + ct * 64;
    unsigned short* dl = Xl + ((size_t)(b * N_ + it * 64)) * C_ + ct * 64;
    #pragma unroll
    for (int rep = 0; rep < 4; ++rep) {
        int idx = rep * 256 + t;
        int i   = idx >> 4;
        int c4  = (idx & 15) * 4;
        ushort4 hv, lv;
        {
            float f0 = tile[c4 + 0][i], f1 = tile[c4 + 1][i];
            float f2 = tile[c4 + 2][i], f3 = tile[c4 + 3][i];
            hv.x = f2bf(f0); lv.x = f2bf(f0 - bf2f(hv.x));
            hv.y = f2bf(f1); lv.y = f2bf(f1 - bf2f(hv.y));
            hv.z = f2bf(f2); lv.z = f2bf(f2 - bf2f(hv.z));
            hv.w = f2bf(f3); lv.w = f2bf(f3 - bf2f(hv.w));
        }
        *(ushort4*)(dh + (size_t)i * C_ + c4) = hv;
        *(ushort4*)(dl + (size_t)i * C_ + c4) = lv;
    }
}

// ---------- pre-pass 2: V[b][c][i] f32 -> fragment-tiled bf16 (hi only) ----------
// layout: [b][ctile (c/16)][ik (i/32)][lg (i8-group)][lr (c-in-tile)][e (i elem)]
__global__ __launch_bounds__(256)
void cvt_v_tiled(const float* __restrict__ X, unsigned short* __restrict__ Xp)
{
    const int gid   = (int)blockIdx.x * 256 + (int)threadIdx.x;
    const int lr    = gid & 15;
    const int lg    = (gid >> 4) & 3;
    const int ik    = (gid >> 6) & 127;
    const int ctile = (gid >> 13) & 31;
    const int b     = gid >> 18;
    const int c     = ctile * 16 + lr;
    const int i     = ik * 32 + lg * 8;
    const float* s  = X + ((size_t)(b * C_ + c)) * N_ + i;
    const float4 a  = *(const float4*)s;
    const float4 d  = *(const float4*)(s + 4);
    unsigned short hv[8];
    hv[0] = f2bf(a.x); hv[1] = f2bf(a.y); hv[2] = f2bf(a.z); hv[3] = f2bf(a.w);
    hv[4] = f2bf(d.x); hv[5] = f2bf(d.y); hv[6] = f2bf(d.z); hv[7] = f2bf(d.w);
    const int off = (b << 21) + (ctile << 16) + (ik << 9) + (lg << 7) + (lr << 3);
    *(uint4*)(Xp + off) = *(const uint4*)hv;
}

// ---------- main fused flash-attention kernel ----------
// grid = 256*nsplit, 512 thr = 8 waves: iw=w&3 (32 i-rows), jw=w>>2 (32 j-cols).
// K/Q LDS: memrow m=idx>>1, 128B rows [even|odd], 16B-quad XOR-swizzled by (m&7).
// 2-deep chunk pipeline: load ck+2 (regs) | store ck+1 (LDS) | MFMA ck | barrier.
__global__ __launch_bounds__(512, 4)
void attn_mfma5(const unsigned short* __restrict__ Kth,
                const unsigned short* __restrict__ Ktl,
                const unsigned short* __restrict__ Qth,
                const unsigned short* __restrict__ Qtl,
                const unsigned short* __restrict__ Vp,
                const float* __restrict__ Qorig,
                float* __restrict__ Out,
                unsigned short* __restrict__ Opart,
                float* __restrict__ ml,
                int nsplit, int niblk)
{
    __shared__ unsigned short KhL[2][4096];   // 8 KB per buf
    __shared__ unsigned short KlL[2][4096];
    __shared__ unsigned short QhL[2][2048];   // 4 KB per buf
    __shared__ unsigned short QlL[2][2048];
    __shared__ unsigned short Pt[JT * IB];    // 16 KB, XOR-swizzled [j][i]
    __shared__ float red_max[4][JT];
    __shared__ float red_sum[4][JT];

    const int t    = (int)threadIdx.x;
    const int w    = t >> 6;
    const int lane = t & 63;
    const int lr   = lane & 15;
    const int lg   = lane >> 4;
    const int iw   = w & 3;
    const int jw   = w >> 2;

    // XCD swizzle; CRITICAL: s is the INNER bit so each XCD gets a compact
    // pj range (32 j-tiles -> Q working set ~4MB = L2) with both splits.
    const int nwg  = 256 * nsplit;
    const int q8   = nwg >> 3;
    const int wgid = ((int)blockIdx.x & 7) * q8 + ((int)blockIdx.x >> 3);
    const int s    = (nsplit == 2) ? (wgid & 1) : 0;
    const int pj   = (nsplit == 2) ? (wgid >> 1) : wgid;
    const int b    = pj >> 6;
    const int j0   = (pj & 63) * JT;
    const int bN   = b * N_;
    const int ibase = s * (N_ / 2) * (nsplit == 2 ? 1 : 0);

    // fragment read byte-offsets
    int offK[2], offQ[2];
    #pragma unroll
    for (int it = 0; it < 2; ++it) {
        const int i = iw * 32 + it * 16 + lr, m = i >> 1;
        offK[it] = m * 128 + (((((i & 1) << 2) + lg) ^ (m & 7)) << 4);
    }
    #pragma unroll
    for (int jt = 0; jt < 2; ++jt) {
        const int j = jw * 32 + jt * 16 + lr, m = j >> 1;
        offQ[jt] = m * 128 + (((((j & 1) << 2) + lg) ^ (m & 7)) << 4);
    }

    // staging decomposition + swizzled LDS write offsets
    const int ist = t >> 2, cst = (t & 3) * 8;    // K: 128 rows x 32 ch, 16B
    const int jst = t >> 3, cqst = (t & 7) * 4;   // Q: 64 rows x 32 ch, 8B
    const int mK = ist >> 1;
    const int wKo = mK * 128 + (((((ist & 1) << 2) | (t & 3)) ^ (mK & 7)) << 4);
    const int mQ = jst >> 1;
    const int wQo = mQ * 128 + (((((jst & 1) << 2) | ((t & 7) >> 1)) ^ (mQ & 7)) << 4) + (t & 1) * 8;

    // two register staging sets (A/B), statically named (rule #20)
    uint4 khA = {0,0,0,0}, klA = {0,0,0,0}, khB = {0,0,0,0}, klB = {0,0,0,0};
    uint2 qhA = {0,0}, qlA = {0,0}, qhB = {0,0}, qlB = {0,0};

    auto loadA = [&](int i0abs, int c0) {
        const size_t kb = ((size_t)(bN + i0abs + ist)) * C_ + c0 + cst;
        khA = *(const uint4*)(Kth + kb);
        klA = *(const uint4*)(Ktl + kb);
        const size_t qb = ((size_t)(bN + j0 + jst)) * C_ + c0 + cqst;
        qhA = *(const uint2*)(Qth + qb);
        qlA = *(const uint2*)(Qtl + qb);
    };
    auto loadB = [&](int i0abs, int c0) {
        const size_t kb = ((size_t)(bN + i0abs + ist)) * C_ + c0 + cst;
        khB = *(const uint4*)(Kth + kb);
        klB = *(const uint4*)(Ktl + kb);
        const size_t qb = ((size_t)(bN + j0 + jst)) * C_ + c0 + cqst;
        qhB = *(const uint2*)(Qth + qb);
        qlB = *(const uint2*)(Qtl + qb);
    };
    auto storeA = [&](int d) {
        *(uint4*)((char*)KhL[d] + wKo) = khA;
        *(uint4*)((char*)KlL[d] + wKo) = klA;
        *(uint2*)((char*)QhL[d] + wQo) = qhA;
        *(uint2*)((char*)QlL[d] + wQo) = qlA;
    };
    auto storeB = [&](int d) {
        *(uint4*)((char*)KhL[d] + wKo) = khB;
        *(uint4*)((char*)KlL[d] + wKo) = klB;
        *(uint2*)((char*)QhL[d] + wQo) = qhB;
        *(uint2*)((char*)QlL[d] + wQo) = qlB;
    };

    float m_run = -INFINITY;   // lane = j (redundant per wave)
    float l_run = 0.0f;

    f32x4 Oacc[4][4];
    #pragma unroll
    for (int a = 0; a < 4; ++a)
        #pragma unroll
        for (int c = 0; c < 4; ++c) Oacc[a][c] = (f32x4)0.0f;

    f32x4 Sacc[2][2];

    // prologue: buf0 <- ck0; regsA <- ck1
    loadA(ibase, 0);
    storeA(0);
    loadA(ibase, KC);
    __syncthreads();

    for (int ib = 0; ib < niblk; ++ib) {
        const int i0 = ibase + ib * IB;

        #pragma unroll
        for (int x = 0; x < 2; ++x)
            #pragma unroll
            for (int y = 0; y < 2; ++y) Sacc[x][y] = (f32x4)0.0f;

        auto mfma_chunk = [&](int d) {
            const char* kh = (const char*)KhL[d];
            const char* kl = (const char*)KlL[d];
            const char* qh = (const char*)QhL[d];
            const char* ql = (const char*)QlL[d];
            bf16x8 bqh[2], bql[2];
            #pragma unroll
            for (int jt = 0; jt < 2; ++jt) {
                bqh[jt] = *(const bf16x8*)(qh + offQ[jt]);
                bql[jt] = *(const bf16x8*)(ql + offQ[jt]);
            }
            __builtin_amdgcn_s_setprio(1);
            #pragma unroll
            for (int it = 0; it < 2; ++it) {
                const bf16x8 akh = *(const bf16x8*)(kh + offK[it]);
                const bf16x8 akl = *(const bf16x8*)(kl + offK[it]);
                #pragma unroll
                for (int jt = 0; jt < 2; ++jt) {
                    Sacc[it][jt] = __builtin_amdgcn_mfma_f32_16x16x32_bf16(akh, bqh[jt], Sacc[it][jt], 0, 0, 0);
                    Sacc[it][jt] = __builtin_amdgcn_mfma_f32_16x16x32_bf16(akh, bql[jt], Sacc[it][jt], 0, 0, 0);
                    Sacc[it][jt] = __builtin_amdgcn_mfma_f32_16x16x32_bf16(akl, bqh[jt], Sacc[it][jt], 0, 0, 0);
                }
            }
            __builtin_amdgcn_s_setprio(0);
        };

        // ---- phase A: 16 chunks, 2-deep pipeline, 1 barrier per chunk ----
        #pragma unroll
        for (int ck = 0; ck < NCH; ck += 2) {
            {   // even chunk ck: compute buf0-parity
                const int cn = ck + 2;
                const bool ok = (cn < NCH) || (ib + 1 < niblk);
                const int ia = (cn < NCH) ? i0 : (i0 + IB);
                const int ca = ((cn < NCH) ? cn : (cn - NCH)) * KC;
                if (ok) loadB(ia, ca);
                storeA((ck + 1) & 1);
                mfma_chunk(ck & 1);
                __syncthreads();
            }
            {   // odd chunk ck+1
                const int cn = ck + 3;
                const bool ok = (cn < NCH) || (ib + 1 < niblk);
                const int ia = (cn < NCH) ? i0 : (i0 + IB);
                const int ca = ((cn < NCH) ? cn : (cn - NCH)) * KC;
                if (ok) loadA(ia, ca);
                storeB((ck + 2) & 1);
                mfma_chunk((ck + 1) & 1);
                __syncthreads();
            }
        }
        // invariant restored: buf0 = next-block ck0, regsA = next-block ck1

        // ---- per-column block max -> red_max[iw][j] ----
        #pragma unroll
        for (int jt = 0; jt < 2; ++jt) {
            float mx = -INFINITY;
            #pragma unroll
            for (int it = 0; it < 2; ++it)
                #pragma unroll
                for (int r = 0; r < 4; ++r) mx = fmaxf(mx, Sacc[it][jt][r]);
            mx = fmaxf(mx, __shfl_xor(mx, 16));
            mx = fmaxf(mx, __shfl_xor(mx, 32));
            if (lane < 16) red_max[iw][jw * 32 + jt * 16 + lane] = mx;
        }
        __syncthreads();   // bar1

        // ---- running max + scale (redundant per wave, lane = j) ----
        float bm = fmaxf(fmaxf(red_max[0][lane], red_max[1][lane]),
                         fmaxf(red_max[2][lane], red_max[3][lane]));
        const float m_new = fmaxf(m_run, bm);
        const float scale = __expf(m_run - m_new);
        m_run = m_new;

        // ---- exp, Pt write (swizzled), partial sums ----
        #pragma unroll
        for (int jt = 0; jt < 2; ++jt) {
            const int j = jw * 32 + jt * 16 + lr;
            const float mcol = __shfl(m_new, j);
            float csum = 0.0f;
            #pragma unroll
            for (int it = 0; it < 2; ++it) {
                const float p0 = __expf(Sacc[it][jt][0] - mcol);
                const float p1 = __expf(Sacc[it][jt][1] - mcol);
                const float p2 = __expf(Sacc[it][jt][2] - mcol);
                const float p3 = __expf(Sacc[it][jt][3] - mcol);
                csum += (p0 + p1) + (p2 + p3);
                ushort4 pk;
                pk.x = f2bf(p0); pk.y = f2bf(p1); pk.z = f2bf(p2); pk.w = f2bf(p3);
                const int i = iw * 32 + it * 16 + lg * 4;
                const unsigned byteoff =
                    ((unsigned)(j * (IB * 2) + i * 2)) ^ (((unsigned)(j & 7)) << 4);
                *(ushort4*)((char*)Pt + byteoff) = pk;
            }
            csum += __shfl_xor(csum, 16);
            csum += __shfl_xor(csum, 32);
            if (lane < 16) red_sum[iw][j] = csum;
        }
        // ---- O rescale (phase-B mapping: j = jt*16+lr) ----
        {
            float scB[4];
            #pragma unroll
            for (int jt = 0; jt < 4; ++jt) scB[jt] = __shfl(scale, jt * 16 + lr);
            #pragma unroll
            for (int ct = 0; ct < 4; ++ct)
                #pragma unroll
                for (int jt = 0; jt < 4; ++jt) {
                    Oacc[ct][jt][0] *= scB[jt];
                    Oacc[ct][jt][1] *= scB[jt];
                    Oacc[ct][jt][2] *= scB[jt];
                    Oacc[ct][jt][3] *= scB[jt];
                }
        }
        __syncthreads();   // bar2: Pt + red_sum visible

        // ---- running denominator ----
        l_run = l_run * scale +
                (red_sum[0][lane] + red_sum[1][lane]) +
                (red_sum[2][lane] + red_sum[3][lane]);

        // ---- phase B: Oacc += V_block * P (V from fragment-tiled global) ----
        {
            const int ikb = i0 >> 5;
            const int fb  = (lg << 7) + (lr << 3);
            const int bb  = b << 21;
            #pragma unroll
            for (int ks = 0; ks < 4; ++ks) {
                bf16x8 pf[4];
                #pragma unroll
                for (int jt = 0; jt < 4; ++jt) {
                    const int j = jt * 16 + lr;
                    const unsigned byteoff =
                        ((unsigned)(j * (IB * 2) + ks * 64 + lg * 16)) ^ (((unsigned)(j & 7)) << 4);
                    pf[jt] = *(const bf16x8*)((char*)Pt + byteoff);
                }
                __builtin_amdgcn_s_setprio(1);
                #pragma unroll
                for (int ct = 0; ct < 4; ++ct) {
                    const int vidx = bb + ((w * 4 + ct) << 16) + ((ikb + ks) << 9) + fb;
                    const bf16x8 vf = *(const bf16x8*)(Vp + vidx);
                    #pragma unroll
                    for (int jt = 0; jt < 4; ++jt)
                        Oacc[ct][jt] = __builtin_amdgcn_mfma_f32_16x16x32_bf16(vf, pf[jt], Oacc[ct][jt], 0, 0, 0);
                }
                __builtin_amdgcn_s_setprio(0);
            }
        }
    }

    // ---- epilogue ----
    const int c0w = w * 64;
    if (nsplit == 1) {
        float il[4];
        #pragma unroll
        for (int jt = 0; jt < 4; ++jt) il[jt] = 1.0f / __shfl(l_run, jt * 16 + lr);
        #pragma unroll
        for (int ct = 0; ct < 4; ++ct) {
            #pragma unroll
            for (int r = 0; r < 4; ++r) {
                const int c = c0w + ct * 16 + lg * 4 + r;
                const float* qrow = Qorig + ((size_t)(b * C_ + c)) * N_ + j0;
                float*       orow = Out   + ((size_t)(b * C_ + c)) * N_ + j0;
                #pragma unroll
                for (int jt = 0; jt < 4; ++jt) {
                    const int j = jt * 16 + lr;
                    orow[j] = qrow[j] + Oacc[ct][jt][r] * il[jt];
                }
            }
        }
    } else {
        if (w == 0) {
            const size_t mb = ((size_t)(s * 256 + pj)) * 2 * 64;
            ml[mb + lane]      = m_run;
            ml[mb + 64 + lane] = l_run;
        }
        const size_t obase = ((size_t)(s * 256 + pj)) * (C_ * (size_t)JT);
        #pragma unroll
        for (int ct = 0; ct < 4; ++ct) {
            #pragma unroll
            for (int r = 0; r < 4; ++r) {
                const int c = c0w + ct * 16 + lg * 4 + r;
                #pragma unroll
                for (int jt = 0; jt < 4; ++jt)
                    Opart[obase + (size_t)c * JT + jt * 16 + lr] = f2bf(Oacc[ct][jt][r]);
            }
        }
    }
}

// ---------- combine two i-split partials ----------
__global__ __launch_bounds__(256)
void combine2(const unsigned short* __restrict__ Opart,
              const float* __restrict__ ml,
              const float* __restrict__ Qorig,
              float* __restrict__ Out)
{
    __shared__ float wi0[64], wi1[64];
    const int pj = (int)blockIdx.x;
    const int t  = (int)threadIdx.x;
    const int b  = pj >> 6;
    const int j0 = (pj & 63) * 64;
    if (t < 64) {
        const size_t m0b = ((size_t)pj) * 2 * 64;
        const size_t m1b = ((size_t)(256 + pj)) * 2 * 64;
        const float m0 = ml[m0b + t], l0 = ml[m0b + 64 + t];
        const float m1 = ml[m1b + t], l1 = ml[m1b + 64 + t];
        const float M  = fmaxf(m0, m1);
        const float w0 = __expf(m0 - M), w1 = __expf(m1 - M);
        const float den = w0 * l0 + w1 * l1;
        wi0[t] = w0 / den;
        wi1[t] = w1 / den;
    }
    __syncthreads();
    const size_t base0 = ((size_t)pj) * (C_ * 64);
    const size_t base1 = ((size_t)(256 + pj)) * (C_ * 64);
    #pragma unroll 4
    for (int rep = 0; rep < 16; ++rep) {
        const int task = rep * 256 + t;
        const int c  = task >> 3;
        const int jg = (task & 7) * 8;
        const ushort4 a0 = *(const ushort4*)(Opart + base0 + (size_t)c * 64 + jg);
        const ushort4 a1 = *(const ushort4*)(Opart + base0 + (size_t)c * 64 + jg + 4);
        const ushort4 b0 = *(const ushort4*)(Opart + base1 + (size_t)c * 64 + jg);
        const ushort4 b1 = *(const ushort4*)(Opart + base1 + (size_t)c * 64 + jg + 4);
        const float* qp = Qorig + ((size_t)(b * C_ + c)) * N_ + j0 + jg;
        float*       op = Out   + ((size_t)(b * C_ + c)) * N_ + j0 + jg;
        op[0] = qp[0] + wi0[jg + 0] * bf2f(a0.x) + wi1[jg + 0] * bf2f(b0.x);
        op[1] = qp[1] + wi0[jg + 1] * bf2f(a0.y) + wi1[jg + 1] * bf2f(b0.y);
        op[2] = qp[2] + wi0[jg + 2] * bf2f(a0.z) + wi1[jg + 2] * bf2f(b0.z);
        op[3] = qp[3] + wi0[jg + 3] * bf2f(a0.w) + wi1[jg + 3] * bf2f(b0.w);
        op[4] = qp[4] + wi0[jg + 4] * bf2f(a1.x) + wi1[jg + 4] * bf2f(b1.x);
        op[5] = qp[5] + wi0[jg + 5] * bf2f(a1.y) + wi1[jg + 5] * bf2f(b1.y);
        op[6] = qp[6] + wi0[jg + 6] * bf2f(a1.z) + wi1[jg + 6] * bf2f(b1.z);
        op[7] = qp[7] + wi0[jg + 7] * bf2f(a1.w) + wi1[jg + 7] * bf2f(b1.w);
    }
}

// ---------- fallback (round-1 f32 kernel) if workspace is too small ----------
namespace {
constexpr int FJT = 32, FIB = 64, FTPB = 256, FNJT = N_ / FJT;
}
__global__ __launch_bounds__(FTPB, 2)
void attn_fused_f32(const float* __restrict__ Q,
                    const float* __restrict__ K,
                    const float* __restrict__ V,
                    float* __restrict__ O)
{
    __shared__ float q_lds[C_][FJT];
    __shared__ float p_t[FJT][FIB + 4];
    __shared__ float red_max[8][FJT];
    __shared__ float red_sum[8][FJT];

    const int t  = (int)threadIdx.x;
    const int j  = t & (FJT - 1);
    const int g  = t >> 5;
    const int b  = (int)blockIdx.x / FNJT;
    const int j0 = ((int)blockIdx.x % FNJT) * FJT;

    const float* Qb = Q + ((size_t)b * C_) * N_ + j0;
    const float* Kb = K + ((size_t)b * C_) * N_;
    const float* Vb = V + ((size_t)b * C_) * N_;
    float*       Ob = O + ((size_t)b * C_) * N_ + j0;

    #pragma unroll 4
    for (int r = 0; r < (C_ * FJT) / FTPB; ++r) {
        int idx = r * FTPB + t;
        q_lds[idx >> 5][idx & (FJT - 1)] = Qb[(size_t)(idx >> 5) * N_ + (idx & (FJT - 1))];
    }
    __syncthreads();

    float acc[64];
    #pragma unroll
    for (int x = 0; x < 64; ++x) acc[x] = 0.0f;
    float m_run = -INFINITY, l_run = 0.0f;

    for (int i0 = 0; i0 < N_; i0 += FIB) {
        float s_acc[8];
        #pragma unroll
        for (int r = 0; r < 8; ++r) s_acc[r] = 0.0f;
        const float* kp = Kb + i0 + g * 8;
        #pragma unroll 4
        for (int c = 0; c < C_; ++c) {
            float qv = q_lds[c][j];
            const float4 k0 = *(const float4*)(kp + (size_t)c * N_);
            const float4 k1 = *(const float4*)(kp + (size_t)c * N_ + 4);
            s_acc[0] = fmaf(k0.x, qv, s_acc[0]); s_acc[1] = fmaf(k0.y, qv, s_acc[1]);
            s_acc[2] = fmaf(k0.z, qv, s_acc[2]); s_acc[3] = fmaf(k0.w, qv, s_acc[3]);
            s_acc[4] = fmaf(k1.x, qv, s_acc[4]); s_acc[5] = fmaf(k1.y, qv, s_acc[5]);
            s_acc[6] = fmaf(k1.z, qv, s_acc[6]); s_acc[7] = fmaf(k1.w, qv, s_acc[7]);
        }
        float tmax = fmaxf(fmaxf(fmaxf(s_acc[0], s_acc[1]), fmaxf(s_acc[2], s_acc[3])),
                           fmaxf(fmaxf(s_acc[4], s_acc[5]), fmaxf(s_acc[6], s_acc[7])));
        red_max[g][j] = tmax;
        __syncthreads();
        float bmax = red_max[0][j];
        #pragma unroll
        for (int gg = 1; gg < 8; ++gg) bmax = fmaxf(bmax, red_max[gg][j]);
        float new_m = fmaxf(m_run, bmax);
        float scale = __expf(m_run - new_m);
        float psum = 0.0f, pv[8];
        #pragma unroll
        for (int r = 0; r < 8; ++r) { pv[r] = __expf(s_acc[r] - new_m); psum += pv[r]; }
        #pragma unroll
        for (int r = 0; r < 8; ++r) p_t[j][g * 8 + r] = pv[r];
        red_sum[g][j] = psum;
        __syncthreads();
        float bsum = 0.0f;
        #pragma unroll
        for (int gg = 0; gg < 8; ++gg) bsum += red_sum[gg][j];
        l_run = l_run * scale + bsum;
        m_run = new_m;
        #pragma unroll
        for (int x = 0; x < 64; ++x) acc[x] *= scale;
        const float* vp = Vb + (size_t)(g * 64) * N_ + i0;
        for (int i4 = 0; i4 < 16; ++i4) {
            const float4 p4 = *(const float4*)&p_t[j][i4 * 4];
            const float* vpi = vp + i4 * 4;
            #pragma unroll
            for (int cq = 0; cq < 4; ++cq) {
                #pragma unroll
                for (int ci = 0; ci < 16; ++ci) {
                    const int cc = cq * 16 + ci;
                    const float4 vv = *(const float4*)(vpi + (size_t)cc * N_);
                    acc[cc] = fmaf(vv.x, p4.x, acc[cc]);
                    acc[cc] = fmaf(vv.y, p4.y, acc[cc]);
                    acc[cc] = fmaf(vv.z, p4.z, acc[cc]);
                    acc[cc] = fmaf(vv.w, p4.w, acc[cc]);
                }
                asm volatile("" ::: "memory");
            }
        }
    }
    const float inv_l = 1.0f / l_run;
    #pragma unroll
    for (int cc = 0; cc < 64; ++cc) {
        const int c = g * 64 + cc;
        Ob[(size_t)c * N_ + j] = q_lds[c][j] + acc[cc] * inv_l;
    }
}

extern "C" void kernel_launch(void* const* d_in, const int* in_sizes, int n_in,
                              void* d_out, int out_size, void* d_ws, size_t ws_size,
                              hipStream_t stream) {
    const float* Q = (const float*)d_in[0];
    const float* K = (const float*)d_in[1];
    const float* V = (const float*)d_in[2];
    float* O = (float*)d_out;

    const size_t EL    = (size_t)B_ * C_ * N_;                 // 8388608
    const size_t NEED1 = EL * 2 * 5;                           // 80 MiB
    const size_t NEED2 = NEED1 + EL * 2 * 2 + 2 * 256 * 2 * 64 * sizeof(float);

    if (ws_size >= NEED1) {
        unsigned short* Kth = (unsigned short*)d_ws;
        unsigned short* Ktl = Kth + EL;
        unsigned short* Qth = Ktl + EL;
        unsigned short* Qtl = Qth + EL;
        unsigned short* Vpp = Qtl + EL;
        cvt_transpose_split<<<dim3(2048), dim3(256), 0, stream>>>(K, Kth, Ktl);
        cvt_transpose_split<<<dim3(2048), dim3(256), 0, stream>>>(Q, Qth, Qtl);
        cvt_v_tiled<<<dim3(4096), dim3(256), 0, stream>>>(V, Vpp);
        if (ws_size >= NEED2) {
            unsigned short* Opart = Vpp + EL;
            float* ml = (float*)(Opart + 2 * EL);
            attn_mfma5<<<dim3(512), dim3(512), 0, stream>>>(
                Kth, Ktl, Qth, Qtl, Vpp, Q, O, Opart, ml, 2, NIB / 2);
            combine2<<<dim3(256), dim3(256), 0, stream>>>(Opart, ml, Q, O);
        } else {
            attn_mfma5<<<dim3(256), dim3(512), 0, stream>>>(
                Kth, Ktl, Qth, Qtl, Vpp, Q, O, nullptr, nullptr, 1, NIB);
        }
    } else {
        attn_fused_f32<<<dim3(B_ * FNJT), dim3(FTPB), 0, stream>>>(Q, K, V, O);
    }
}